// Round 15
// baseline (97.773 us; speedup 1.0000x reference)
//
#include <hip/hip_runtime.h>
#include <math.h>

typedef __attribute__((ext_vector_type(8))) short s16x8;
typedef __attribute__((ext_vector_type(4))) float f32x4;
typedef __attribute__((ext_vector_type(2))) float f32x2;

#define LOG2E 1.4426950408889634f

// ---- workspace layout (float offsets) ----
#define OFF_XH   0           // xh bf16 NHWC [4][4096][256] = 2,097,152 floats
#define OFF_WB   2097152     // conv1 weights bf16 MFMA layout [ch2][ck8][tap9][g4][co64][j8]
#define OFF_PQT  2244608     // [ic16][part8][o128][4] = coalesced {A,B,P',D'}
#define OFF_W2   2310144     // W2cat [21][256] = [w2 | w2@base_w]

// ---------------- fused prologue: transpose x | prep weights | w2b ---------
__global__ __launch_bounds__(256) void prep_all_k(
    const float* __restrict__ x, const float* __restrict__ w1,
    const float* __restrict__ ks, const float* __restrict__ kt,
    const float* __restrict__ kw, const float* __restrict__ kb,
    const float* __restrict__ w2, float* __restrict__ ws) {
  int blk = blockIdx.x;
  int t = threadIdx.x;
  if (blk < 1024) {
    __shared__ float lsm[64][65];
    unsigned short* xh = (unsigned short*)(ws + OFF_XH);
    int pr = blk & 63, cib = (blk >> 6) & 3, bb = blk >> 8;
    int sp0 = pr * 64;
    const float* src = x + (unsigned)(bb * 256 + cib * 64) * 4096 + sp0;
#pragma unroll
    for (int rr = 0; rr < 16; ++rr) {
      int idx = rr * 256 + t;
      int ci = idx >> 6, px = idx & 63;
      lsm[ci][px] = src[ci * 4096 + px];
    }
    __syncthreads();
#pragma unroll
    for (int rr = 0; rr < 16; ++rr) {
      int idx = rr * 256 + t;
      int px = idx >> 6, ci = idx & 63;
      unsigned u = __float_as_uint(lsm[ci][px]);
      xh[(unsigned)(bb * 4096 + sp0 + px) * 256 + cib * 64 + ci] =
          (unsigned short)((u + 0x7FFF + ((u >> 16) & 1)) >> 16);
    }
  } else if (blk < 2251) {
    int tid = (blk - 1024) * 256 + t;
    unsigned short* Wb = (unsigned short*)(ws + OFF_WB);
    if (tid < 294912) {
      int j = tid & 7, co = (tid >> 3) & 63, g = (tid >> 9) & 3, r = tid >> 11;
      int t9 = r % 9, q = r / 9, ck = q & 7, chh = q >> 3;
      int ci = ck * 32 + g * 8 + j, cog = chh * 64 + co;
      unsigned u = __float_as_uint(w1[(unsigned)(cog * 256 + ci) * 9 + t9]);
      Wb[tid] = (unsigned short)((u + 0x7FFF + ((u >> 16) & 1)) >> 16);
    } else if (tid < 294912 + 16384) {
      int i2 = tid - 294912;
      int i = i2 >> 7, o = i2 & 127;
      int ic = i >> 3, k = i & 7;
      float rs = 1.f / ks[o * 128 + i];
      float T  = kt[o * 128 + i];
      float A  = -0.7213475204444817f * rs * rs;   // Q
      float Bq = -2.f * A * T;
      float C  = A * T * T;
      float P0 = -rs * kw[o * 128 + i];
      float sc = exp2f(C);
      int khi = k >> 2, klo = k & 3;
      unsigned base = ((unsigned)ic * 8 * 128 + o) * 4 + klo;  // + part*512
      ws[OFF_PQT + base + (0 + khi) * 512] = A;
      ws[OFF_PQT + base + (2 + khi) * 512] = Bq;
      ws[OFF_PQT + base + (4 + khi) * 512] = P0 * sc;
      ws[OFF_PQT + base + (6 + khi) * 512] = -P0 * T * sc;
    } else if (tid < 294912 + 16384 + 2688) {
      int i3 = tid - 294912 - 16384;
      int nc = i3 >> 7, k = i3 & 127;
      ws[OFF_W2 + nc * 256 + k] = w2[nc * 128 + k];
    }
  } else {
    int nc = blk - 2251;
    if (t < 128) {
      float acc = 0.f;
      for (int o = 0; o < 128; ++o)
        acc = fmaf(w2[nc * 128 + o], kb[o * 128 + t], acc);
      ws[OFF_W2 + nc * 256 + 128 + t] = acc;
    }
  }
}

// ---------------- fused conv1 + wavkan + conv2 ------------------------------
// r15: wavkan alone is pinned at ~46us across 7 structures (issue-floor
// ~28us + irreducible idle). Fusion puts conv1's MFMA work (different pipe)
// under wavkan's idle across desynced blocks, and h/k_wav never leave LDS.
// Block = 32 px (x-half of one y-row) x 128 co; 512 thr = 8 waves; grid 512.
// conv1: two 64-co passes, wave tile 16px x 16co (Mr=1,Nr=1), per ck:
//   {stage A + B(p0); sync; mfma p0; sync; stage B(p1); sync; mfma p1; sync}.
// Epilogue -> hsm f32 [32][132] (aliases Asm/Bsm, all-sync'd).
// wavkan: r13-proven body, h from hsm broadcast reads, k -> ksm.
// conv2: silu in-place on hsm, then 32px x 21nc dot from ksm|hsm.
__global__ __launch_bounds__(512) void fused_k(
    const unsigned short* __restrict__ xh, const unsigned short* __restrict__ Wb,
    const float* __restrict__ b1, const float* __restrict__ PQT,
    const float* __restrict__ w2c, const float* __restrict__ b2,
    float* __restrict__ out) {
  __shared__ __align__(16) char smem[46080];
  unsigned short* Asm = (unsigned short*)smem;            // [3][34][40] = 8160 B
  unsigned short* Bsm = (unsigned short*)(smem + 8160);   // 18432 sh = 36864 B
  float* hsm = (float*)smem;                              // [32][132] 16896 B
  float* ksm = (float*)(smem + 16896);                    // [32][132] 16896 B

  int blk = blockIdx.x;
  int xh2 = blk & 1, y = (blk >> 1) & 63, bb = blk >> 7;
  int x0 = xh2 * 32;
  int t = threadIdx.x;
  int wave = t >> 6, lane = t & 63;
  int pxh = wave & 1, wc = wave >> 1;        // 16-px half, 16-co quarter
  int l15 = lane & 15, lg = lane >> 4;

  f32x4 acc[2];
  acc[0] = (f32x4){0.f, 0.f, 0.f, 0.f};
  acc[1] = acc[0];

  // A staging map (t < 408): 3 rows x 34 cols x 4 quads, zero-filled halo
  int arr = t / 136, arem = t % 136;
  int acx = arem >> 2, aq = arem & 3;
  int agy = y - 1 + arr, agx = x0 - 1 + acx;
  bool aok = (t < 408) & (agy >= 0) & (agy < 64) & (agx >= 0) & (agx < 64);
  const unsigned short* asrc =
      xh + (unsigned)((bb * 4096 + agy * 64 + agx)) * 256 + aq * 8;
  unsigned short* adst = Asm + ((arr * 34 + acx) * 40 + aq * 8);

  for (int ck = 0; ck < 8; ++ck) {
    if (t < 408) {
      float4 v = {0.f, 0.f, 0.f, 0.f};
      if (aok) v = *(const float4*)(asrc + ck * 32);
      *(float4*)adst = v;
    }
    {
      const float4* s = (const float4*)(Wb + (unsigned)ck * 18432);
      float4* d = (float4*)Bsm;
      for (int j = t; j < 2304; j += 512) d[j] = s[j];
    }
    __syncthreads();
#pragma unroll
    for (int t9 = 0; t9 < 9; ++t9) {
      int ky = t9 / 3, kx = t9 % 3;
      s16x8 a = *(const s16x8*)&Asm[(ky * 34 + pxh * 16 + l15 + kx) * 40 + lg * 8];
      s16x8 b = *(const s16x8*)&Bsm[((t9 * 4 + lg) * 64 + wc * 16 + l15) * 8];
      acc[0] = __builtin_amdgcn_mfma_f32_16x16x32_bf16(a, b, acc[0], 0, 0, 0);
    }
    __syncthreads();
    {
      const float4* s = (const float4*)(Wb + (unsigned)(8 + ck) * 18432);
      float4* d = (float4*)Bsm;
      for (int j = t; j < 2304; j += 512) d[j] = s[j];
    }
    __syncthreads();
#pragma unroll
    for (int t9 = 0; t9 < 9; ++t9) {
      int ky = t9 / 3, kx = t9 % 3;
      s16x8 a = *(const s16x8*)&Asm[(ky * 34 + pxh * 16 + l15 + kx) * 40 + lg * 8];
      s16x8 b = *(const s16x8*)&Bsm[((t9 * 4 + lg) * 64 + wc * 16 + l15) * 8];
      acc[1] = __builtin_amdgcn_mfma_f32_16x16x32_bf16(a, b, acc[1], 0, 0, 0);
    }
    __syncthreads();
  }
  // conv1 epilogue: bias+relu -> hsm (aliases Asm/Bsm; all MFMA complete)
#pragma unroll
  for (int pass = 0; pass < 2; ++pass) {
    int co = pass * 64 + wc * 16 + l15;
    float bz = b1[co];
#pragma unroll
    for (int r = 0; r < 4; ++r) {
      int px = pxh * 16 + lg * 4 + r;
      float v = acc[pass][r] + bz;
      hsm[px * 132 + co] = v > 0.f ? v : 0.f;
    }
  }
  __syncthreads();

  // ---- wavkan: wave = 8 px x 64 o-lanes x all 128 i (r13 body) ----
  {
    int oh = wave & 1, pg = wave >> 1;
    int nb = pg * 8;
    int o = oh * 64 + lane;
    f32x2 accv[8];
#pragma unroll
    for (int n = 0; n < 8; ++n) accv[n] = (f32x2){0.f, 0.f};
    const float4* pq = (const float4*)PQT + o;
    for (int ic = 0; ic < 16; ++ic) {
      const float4* pp = pq + (unsigned)ic * 1024;
      float4 r0 = pp[0],   r1 = pp[128], r2 = pp[256], r3 = pp[384],
             r4 = pp[512], r5 = pp[640], r6 = pp[768], r7 = pp[896];
      f32x2 A2[4] = {{r0.x, r0.y}, {r0.z, r0.w}, {r1.x, r1.y}, {r1.z, r1.w}};
      f32x2 B2[4] = {{r2.x, r2.y}, {r2.z, r2.w}, {r3.x, r3.y}, {r3.z, r3.w}};
      f32x2 P2[4] = {{r4.x, r4.y}, {r4.z, r4.w}, {r5.x, r5.y}, {r5.z, r5.w}};
      f32x2 D2[4] = {{r6.x, r6.y}, {r6.z, r6.w}, {r7.x, r7.y}, {r7.z, r7.w}};
      int i0 = ic * 8;
#pragma unroll
      for (int n = 0; n < 8; ++n) {
        const float* hr = &hsm[(nb + n) * 132 + i0];
        float4 h0 = *(const float4*)&hr[0];      // broadcast ds_read
        float4 h1 = *(const float4*)&hr[4];
        f32x2 hh[4] = {{h0.x, h0.y}, {h0.z, h0.w}, {h1.x, h1.y}, {h1.z, h1.w}};
        f32x2 a2 = accv[n];
#pragma unroll
        for (int q = 0; q < 4; ++q) {
          f32x2 h2 = hh[q];
          f32x2 t2 = A2[q] * h2 + B2[q];     // v_pk_fma_f32
          f32x2 u2 = t2 * h2;                // v_pk_mul_f32
          f32x2 e2;
          e2.x = __builtin_amdgcn_exp2f(u2.x);
          e2.y = __builtin_amdgcn_exp2f(u2.y);
          f32x2 v2 = P2[q] * h2 + D2[q];     // v_pk_fma_f32
          a2 = v2 * e2 + a2;                 // v_pk_fma_f32
        }
        accv[n] = a2;
      }
    }
#pragma unroll
    for (int n = 0; n < 8; ++n)
      ksm[(nb + n) * 132 + o] = accv[n].x + accv[n].y;
  }
  __syncthreads();

  // ---- silu(h) in place on hsm ----
  {
    int n = t >> 4, c8 = (t & 15) * 8;
    float* hp = &hsm[n * 132 + c8];
    float4 v0 = *(float4*)&hp[0], v1 = *(float4*)&hp[4];
    float4 s0, s1;
    s0.x = v0.x * __builtin_amdgcn_rcpf(1.f + __builtin_amdgcn_exp2f(-LOG2E * v0.x));
    s0.y = v0.y * __builtin_amdgcn_rcpf(1.f + __builtin_amdgcn_exp2f(-LOG2E * v0.y));
    s0.z = v0.z * __builtin_amdgcn_rcpf(1.f + __builtin_amdgcn_exp2f(-LOG2E * v0.z));
    s0.w = v0.w * __builtin_amdgcn_rcpf(1.f + __builtin_amdgcn_exp2f(-LOG2E * v0.w));
    s1.x = v1.x * __builtin_amdgcn_rcpf(1.f + __builtin_amdgcn_exp2f(-LOG2E * v1.x));
    s1.y = v1.y * __builtin_amdgcn_rcpf(1.f + __builtin_amdgcn_exp2f(-LOG2E * v1.y));
    s1.z = v1.z * __builtin_amdgcn_rcpf(1.f + __builtin_amdgcn_exp2f(-LOG2E * v1.z));
    s1.w = v1.w * __builtin_amdgcn_rcpf(1.f + __builtin_amdgcn_exp2f(-LOG2E * v1.w));
    *(float4*)&hp[0] = s0;
    *(float4*)&hp[4] = s1;
  }
  __syncthreads();

  // ---- conv2: 32 px x 21 nc, K = [ksm | silu hsm] ----
  {
    int n = t & 31, g = t >> 5;          // g in 0..15; nc = g and g+16 (g<5)
    bool has1 = g < 5;
    const float* w0 = w2c + g * 256;
    const float* w1p = w2c + (g + 16) * 256;
    const float* kr = &ksm[n * 132];
    const float* hr = &hsm[n * 132];
    float a0 = 0.f, a1 = 0.f;
#pragma unroll 4
    for (int k4 = 0; k4 < 32; ++k4) {
      float4 kv = *(const float4*)&kr[k4 * 4];
      float4 w = *(const float4*)&w0[k4 * 4];
      a0 += kv.x * w.x + kv.y * w.y + kv.z * w.z + kv.w * w.w;
      if (has1) {
        float4 wB = *(const float4*)&w1p[k4 * 4];
        a1 += kv.x * wB.x + kv.y * wB.y + kv.z * wB.z + kv.w * wB.w;
      }
    }
#pragma unroll 4
    for (int k4 = 0; k4 < 32; ++k4) {
      float4 kv = *(const float4*)&hr[k4 * 4];
      float4 w = *(const float4*)&w0[128 + k4 * 4];
      a0 += kv.x * w.x + kv.y * w.y + kv.z * w.z + kv.w * w.w;
      if (has1) {
        float4 wB = *(const float4*)&w1p[128 + k4 * 4];
        a1 += kv.x * wB.x + kv.y * wB.y + kv.z * wB.z + kv.w * wB.w;
      }
    }
    int sp = y * 64 + x0 + n;
    out[(unsigned)(bb * 21 + g) * 4096 + sp] = a0 + b2[g];
    if (has1) out[(unsigned)(bb * 21 + g + 16) * 4096 + sp] = a1 + b2[g + 16];
  }
}

// ---------------- launch ---------------------------------------------------
extern "C" void kernel_launch(void* const* d_in, const int* in_sizes, int n_in,
                              void* d_out, int out_size, void* d_ws, size_t ws_size,
                              hipStream_t stream) {
  const float* x  = (const float*)d_in[0];
  const float* w1 = (const float*)d_in[1];
  const float* b1 = (const float*)d_in[2];
  const float* ks = (const float*)d_in[3];
  const float* kt = (const float*)d_in[4];
  const float* kw = (const float*)d_in[5];
  const float* kb = (const float*)d_in[6];
  const float* w2 = (const float*)d_in[7];
  const float* b2 = (const float*)d_in[8];
  float* out = (float*)d_out;
  float* ws  = (float*)d_ws;

  prep_all_k<<<2272, 256, 0, stream>>>(x, w1, ks, kt, kw, kb, w2, ws);
  fused_k<<<512, 512, 0, stream>>>((const unsigned short*)(ws + OFF_XH),
                                   (const unsigned short*)(ws + OFF_WB),
                                   b1, ws + OFF_PQT, ws + OFF_W2, b2, out);
}

// Round 16
// 84.851 us; speedup vs baseline: 1.1523x; 1.1523x over previous
//
#include <hip/hip_runtime.h>
#include <math.h>

typedef __attribute__((ext_vector_type(8))) short s16x8;
typedef __attribute__((ext_vector_type(4))) float f32x4;
typedef __attribute__((ext_vector_type(2))) float f32x2;

#define LOG2E 1.4426950408889634f

// ---- workspace layout (float offsets) ----
#define OFF_XH   0           // xh bf16 NHWC [4][4096][256] = 2,097,152 floats
#define OFF_WB   2097152     // conv1 weights bf16 MFMA layout [ch2][ck8][tap9][g4][co64][j8]
#define OFF_PQT  2244608     // [ic16][part8][o128][4] = coalesced {A,B,P',D'}
#define OFF_W2   2310144     // W2cat [21][256] = [w2 | w2@base_w]
#define OFF_H    2315520     // h f32 NHWC [16384][128]

// ---------------- fused prologue: transpose x | prep weights | w2b ---------
__global__ __launch_bounds__(256) void prep_all_k(
    const float* __restrict__ x, const float* __restrict__ w1,
    const float* __restrict__ ks, const float* __restrict__ kt,
    const float* __restrict__ kw, const float* __restrict__ kb,
    const float* __restrict__ w2, float* __restrict__ ws) {
  int blk = blockIdx.x;
  int t = threadIdx.x;
  if (blk < 1024) {
    __shared__ float lsm[64][65];
    unsigned short* xh = (unsigned short*)(ws + OFF_XH);
    int pr = blk & 63, cib = (blk >> 6) & 3, bb = blk >> 8;
    int sp0 = pr * 64;
    const float* src = x + (unsigned)(bb * 256 + cib * 64) * 4096 + sp0;
#pragma unroll
    for (int rr = 0; rr < 16; ++rr) {
      int idx = rr * 256 + t;
      int ci = idx >> 6, px = idx & 63;
      lsm[ci][px] = src[ci * 4096 + px];
    }
    __syncthreads();
#pragma unroll
    for (int rr = 0; rr < 16; ++rr) {
      int idx = rr * 256 + t;
      int px = idx >> 6, ci = idx & 63;
      unsigned u = __float_as_uint(lsm[ci][px]);
      xh[(unsigned)(bb * 4096 + sp0 + px) * 256 + cib * 64 + ci] =
          (unsigned short)((u + 0x7FFF + ((u >> 16) & 1)) >> 16);
    }
  } else if (blk < 2251) {
    // KAN folding: contribution = fma(P',h,D') * exp2(h*fma(A,h,B));
    // A=Q, B=-2QT, P'=P0*2^C, D'=-P0*T*2^C, C=QT^2, Q=-0.5*log2e/s^2, P0=-kw/s.
    // Param layout coalesced: [ic][part8][o128][4f].
    int tid = (blk - 1024) * 256 + t;
    unsigned short* Wb = (unsigned short*)(ws + OFF_WB);
    if (tid < 294912) {
      int j = tid & 7, co = (tid >> 3) & 63, g = (tid >> 9) & 3, r = tid >> 11;
      int t9 = r % 9, q = r / 9, ck = q & 7, chh = q >> 3;
      int ci = ck * 32 + g * 8 + j, cog = chh * 64 + co;
      unsigned u = __float_as_uint(w1[(unsigned)(cog * 256 + ci) * 9 + t9]);
      Wb[tid] = (unsigned short)((u + 0x7FFF + ((u >> 16) & 1)) >> 16);
    } else if (tid < 294912 + 16384) {
      int i2 = tid - 294912;
      int i = i2 >> 7, o = i2 & 127;
      int ic = i >> 3, k = i & 7;
      float rs = 1.f / ks[o * 128 + i];
      float T  = kt[o * 128 + i];
      float A  = -0.7213475204444817f * rs * rs;   // Q
      float Bq = -2.f * A * T;
      float C  = A * T * T;
      float P0 = -rs * kw[o * 128 + i];
      float sc = exp2f(C);
      int khi = k >> 2, klo = k & 3;
      unsigned base = ((unsigned)ic * 8 * 128 + o) * 4 + klo;  // + part*512
      ws[OFF_PQT + base + (0 + khi) * 512] = A;
      ws[OFF_PQT + base + (2 + khi) * 512] = Bq;
      ws[OFF_PQT + base + (4 + khi) * 512] = P0 * sc;
      ws[OFF_PQT + base + (6 + khi) * 512] = -P0 * T * sc;
    } else if (tid < 294912 + 16384 + 2688) {
      int i3 = tid - 294912 - 16384;
      int nc = i3 >> 7, k = i3 & 127;
      ws[OFF_W2 + nc * 256 + k] = w2[nc * 128 + k];
    }
  } else {
    int nc = blk - 2251;
    if (t < 128) {
      float acc = 0.f;
      for (int o = 0; o < 128; ++o)
        acc = fmaf(w2[nc * 128 + o], kb[o * 128 + t], acc);
      ws[OFF_W2 + nc * 256 + 128 + t] = acc;
    }
  }
}

// ---------------- conv1 3x3 as bf16 MFMA implicit GEMM ---------------------
// grid 512 = bb(4) x y(64) x cohalf(2); block 256 = 4 waves; 2 blocks/CU.
// block tile 64M(1y x 64x) x 64N; wave tile 32Mx32N (Mr=2, Nr=2).
__global__ __launch_bounds__(256, 2) void conv1_mfma_k(
    const unsigned short* __restrict__ xh, const unsigned short* __restrict__ Wb,
    const float* __restrict__ b1, float* __restrict__ h) {
  __shared__ unsigned short Asm[3 * 66 * 40];  // [yrow3][x66][ci 32 pad40] 15.8KB
  __shared__ unsigned short Bsm[18432];        // [tap9][g4][co64][j8]      36.9KB
  int blk = blockIdx.x;
  int ch = blk & 1, y = (blk >> 1) & 63, bb = blk >> 7;
  int t = threadIdx.x;
  int wave = t >> 6, lane = t & 63;
  int wx = wave & 1, wn = wave >> 1;
  int l15 = lane & 15, lg = lane >> 4;

  if (t < 6) {  // zero x-halo columns (stay zero across chunks)
    int r = t >> 1, xl = (t & 1) * 65;
    float4 z = {0, 0, 0, 0};
    float4* p = (float4*)&Asm[(r * 66 + xl) * 40];
    p[0] = z; p[1] = z; p[2] = z; p[3] = z; p[4] = z;
  }

  f32x4 acc[2][2];
  f32x4 zz = {0.f, 0.f, 0.f, 0.f};
  acc[0][0] = zz; acc[0][1] = zz; acc[1][0] = zz; acc[1][1] = zz;

  int r_st = t >> 6, x_st = t & 63;
  int gy = y - 1 + r_st;
  bool arow = (r_st < 3);
  bool yok = arow & (gy >= 0) & (gy < 64);
  const unsigned short* asrc = xh + (unsigned)(bb * 4096 + gy * 64 + x_st) * 256;
  unsigned short* adst = &Asm[(r_st * 66 + x_st + 1) * 40];
  const unsigned short* bslab = Wb + ch * 8 * 18432;

  for (int ck = 0; ck < 8; ++ck) {
    float4 v0 = {0, 0, 0, 0}, v1 = v0, v2 = v0, v3 = v0;
    if (yok) {
      const float4* s = (const float4*)(asrc + ck * 32);
      v0 = s[0]; v1 = s[1]; v2 = s[2]; v3 = s[3];
    }
    if (arow) { float4* d = (float4*)adst; d[0] = v0; d[1] = v1; d[2] = v2; d[3] = v3; }
    {
      const float4* s = (const float4*)(bslab + ck * 18432);
      float4* d = (float4*)Bsm;
#pragma unroll
      for (int j = 0; j < 9; ++j) d[j * 256 + t] = s[j * 256 + t];
    }
    __syncthreads();
#pragma unroll
    for (int t9 = 0; t9 < 9; ++t9) {
      int ky = t9 / 3, kx = t9 % 3;
      s16x8 a[2], b[2];
      int abase = (ky * 66 + wx * 32 + l15 + kx) * 40 + lg * 8;
#pragma unroll
      for (int f = 0; f < 2; ++f)
        a[f] = *(const s16x8*)&Asm[abase + f * 640];
#pragma unroll
      for (int n = 0; n < 2; ++n)
        b[n] = *(const s16x8*)&Bsm[((t9 * 4 + lg) * 64 + wn * 32 + n * 16 + l15) * 8];
#pragma unroll
      for (int f = 0; f < 2; ++f)
#pragma unroll
        for (int n = 0; n < 2; ++n)
          acc[f][n] = __builtin_amdgcn_mfma_f32_16x16x32_bf16(a[f], b[n], acc[f][n], 0, 0, 0);
    }
    __syncthreads();
  }
  // epilogue: bias + relu, store h NHWC f32
#pragma unroll
  for (int n = 0; n < 2; ++n) {
    int co = ch * 64 + wn * 32 + n * 16 + l15;
    float bz = b1[co];
#pragma unroll
    for (int f = 0; f < 2; ++f) {
      int xbase = wx * 32 + f * 16 + lg * 4;
      float* dst = h + (unsigned)(bb * 4096 + y * 64 + xbase) * 128 + co;
#pragma unroll
      for (int r = 0; r < 4; ++r) {
        float v = acc[f][n][r] + bz;
        dst[r * 128] = v > 0.f ? v : 0.f;
      }
    }
  }
}

// ---------------- Wav-KAN + fused conv2 ------------------------------------
// r16: r12's proven wavkan structure (grid 2048, 4 waves = ich(2) x oh(2),
// 8 n/block, best measured 46.4us) + conv2 tail in-block. The tail's ~1.5K
// cyc of scalar FMA slots into wavkan's measured ~40% idle across desynced
// blocks; k_wav never leaves LDS (kills 16MB round-trip + conv2 launch).
// r15's mistake (degrading conv1's shape for fusion) is NOT repeated —
// conv1 stays in its best standalone form.
__global__ __launch_bounds__(256) void wavkan_conv2_k(
    const float* __restrict__ h, const float* __restrict__ PQT,
    const float* __restrict__ w2c, const float* __restrict__ b2,
    float* __restrict__ out) {
  __shared__ float hsm[8][132];        // 4.2 KB (pad 132: tail reads row-major)
  __shared__ f32x2 red[2][8][64];      // 8 KB partial sums
  __shared__ float ksm[8][132];        // 4.2 KB k_wav rows
  int n0 = blockIdx.x * 8;
  int t = threadIdx.x;
  {
    int row = t >> 5, c4 = (t & 31) * 4;
    *(float4*)&hsm[row][c4] = *(const float4*)&h[(unsigned)(n0 + row) * 128 + c4];
  }
  __syncthreads();

  int wave = t >> 6, lane = t & 63;
  int ich = wave & 1;            // ic half: 0 -> ic 0..7, 1 -> ic 8..15
  int oh  = wave >> 1;           // o half
  int o   = oh * 64 + lane;

  f32x2 accv[8];
#pragma unroll
  for (int n = 0; n < 8; ++n) accv[n] = (f32x2){0.f, 0.f};

  const float4* pq = (const float4*)PQT + o;   // + (ic*8+part)*128

  for (int ic = ich * 8; ic < ich * 8 + 8; ++ic) {
    const float4* pp = pq + (unsigned)ic * 1024;
    float4 r0 = pp[0],   r1 = pp[128], r2 = pp[256], r3 = pp[384],
           r4 = pp[512], r5 = pp[640], r6 = pp[768], r7 = pp[896];
    f32x2 A2[4] = {{r0.x, r0.y}, {r0.z, r0.w}, {r1.x, r1.y}, {r1.z, r1.w}};
    f32x2 B2[4] = {{r2.x, r2.y}, {r2.z, r2.w}, {r3.x, r3.y}, {r3.z, r3.w}};
    f32x2 P2[4] = {{r4.x, r4.y}, {r4.z, r4.w}, {r5.x, r5.y}, {r5.z, r5.w}};
    f32x2 D2[4] = {{r6.x, r6.y}, {r6.z, r6.w}, {r7.x, r7.y}, {r7.z, r7.w}};
    int i0 = ic * 8;
#pragma unroll
    for (int n = 0; n < 8; ++n) {
      float4 h0 = *(const float4*)&hsm[n][i0];           // broadcast ds_read
      float4 h1 = *(const float4*)&hsm[n][i0 + 4];
      f32x2 hh[4] = {{h0.x, h0.y}, {h0.z, h0.w}, {h1.x, h1.y}, {h1.z, h1.w}};
      f32x2 a2 = accv[n];
#pragma unroll
      for (int q = 0; q < 4; ++q) {
        f32x2 h2 = hh[q];
        f32x2 t2 = A2[q] * h2 + B2[q];     // v_pk_fma_f32
        f32x2 u2 = t2 * h2;                // v_pk_mul_f32
        f32x2 e2;
        e2.x = __builtin_amdgcn_exp2f(u2.x);
        e2.y = __builtin_amdgcn_exp2f(u2.y);
        f32x2 v2 = P2[q] * h2 + D2[q];     // v_pk_fma_f32
        a2 = v2 * e2 + a2;                 // v_pk_fma_f32
      }
      accv[n] = a2;
    }
  }

  // reduce ic-halves: ich=1 waves publish; barrier; ich=0 combine -> ksm.
  if (ich) {
#pragma unroll
    for (int n = 0; n < 8; ++n) red[oh][n][lane] = accv[n];
  }
  __syncthreads();
  if (!ich) {
#pragma unroll
    for (int n = 0; n < 8; ++n) {
      f32x2 r = red[oh][n][lane];
      ksm[n][o] = (accv[n].x + r.x) + (accv[n].y + r.y);
    }
  }
  // silu(h) in place (all hsm reads completed before the barrier above)
  {
    int n = t >> 5, c4 = (t & 31) * 4;
    float4 v = *(float4*)&hsm[n][c4];
    float4 s;
    s.x = v.x * __builtin_amdgcn_rcpf(1.f + __builtin_amdgcn_exp2f(-LOG2E * v.x));
    s.y = v.y * __builtin_amdgcn_rcpf(1.f + __builtin_amdgcn_exp2f(-LOG2E * v.y));
    s.z = v.z * __builtin_amdgcn_rcpf(1.f + __builtin_amdgcn_exp2f(-LOG2E * v.z));
    s.w = v.w * __builtin_amdgcn_rcpf(1.f + __builtin_amdgcn_exp2f(-LOG2E * v.w));
    *(float4*)&hsm[n][c4] = s;
  }
  __syncthreads();

  // conv2 tail: 168 threads, thread (g,n): out[bb][g][sp] over K=[ksm|silu h]
  if (t < 168) {
    int n = t & 7, g = t >> 3;
    const float* w0 = w2c + g * 256;
    const float* kr = &ksm[n][0];
    const float* hr = &hsm[n][0];
    float a0 = 0.f;
#pragma unroll 4
    for (int k4 = 0; k4 < 32; ++k4) {
      float4 kv = *(const float4*)&kr[k4 * 4];
      float4 w = *(const float4*)&w0[k4 * 4];
      a0 += kv.x * w.x + kv.y * w.y + kv.z * w.z + kv.w * w.w;
    }
#pragma unroll 4
    for (int k4 = 0; k4 < 32; ++k4) {
      float4 hv = *(const float4*)&hr[k4 * 4];
      float4 w = *(const float4*)&w0[128 + k4 * 4];
      a0 += hv.x * w.x + hv.y * w.y + hv.z * w.z + hv.w * w.w;
    }
    int gn = n0 + n, bb = gn >> 12, sp = gn & 4095;
    out[(unsigned)(bb * 21 + g) * 4096 + sp] = a0 + b2[g];
  }
}

// ---------------- launch ---------------------------------------------------
extern "C" void kernel_launch(void* const* d_in, const int* in_sizes, int n_in,
                              void* d_out, int out_size, void* d_ws, size_t ws_size,
                              hipStream_t stream) {
  const float* x  = (const float*)d_in[0];
  const float* w1 = (const float*)d_in[1];
  const float* b1 = (const float*)d_in[2];
  const float* ks = (const float*)d_in[3];
  const float* kt = (const float*)d_in[4];
  const float* kw = (const float*)d_in[5];
  const float* kb = (const float*)d_in[6];
  const float* w2 = (const float*)d_in[7];
  const float* b2 = (const float*)d_in[8];
  float* out = (float*)d_out;
  float* ws  = (float*)d_ws;

  prep_all_k<<<2272, 256, 0, stream>>>(x, w1, ks, kt, kw, kb, w2, ws);
  conv1_mfma_k<<<512, 256, 0, stream>>>((const unsigned short*)(ws + OFF_XH),
                                        (const unsigned short*)(ws + OFF_WB),
                                        b1, ws + OFF_H);
  wavkan_conv2_k<<<2048, 256, 0, stream>>>(ws + OFF_H, ws + OFF_PQT,
                                           ws + OFF_W2, b2, out);
}

// Round 17
// 84.606 us; speedup vs baseline: 1.1556x; 1.0029x over previous
//
#include <hip/hip_runtime.h>
#include <math.h>

typedef __attribute__((ext_vector_type(8))) short s16x8;
typedef __attribute__((ext_vector_type(4))) float f32x4;
typedef __attribute__((ext_vector_type(2))) float f32x2;

#define LOG2E 1.4426950408889634f

// ---- workspace layout (float offsets) ----
#define OFF_XH   0           // xh bf16 NHWC [4][4096][256] = 2,097,152 floats
#define OFF_WB   2097152     // conv1 weights bf16 MFMA layout [ch2][ck8][tap9][g4][co64][j8]
#define OFF_PQT  2244608     // [ic16][part8][o128][4] = coalesced {A,B,P',D'}
#define OFF_W2   2310144     // W2cat [21][256] = [w2 | w2@base_w]
#define OFF_H    2315520     // h f32 NHWC [16384][128]

// ---------------- fused prologue: transpose x | prep weights | w2b ---------
__global__ __launch_bounds__(256) void prep_all_k(
    const float* __restrict__ x, const float* __restrict__ w1,
    const float* __restrict__ ks, const float* __restrict__ kt,
    const float* __restrict__ kw, const float* __restrict__ kb,
    const float* __restrict__ w2, float* __restrict__ ws) {
  int blk = blockIdx.x;
  int t = threadIdx.x;
  if (blk < 1024) {
    __shared__ float lsm[64][65];
    unsigned short* xh = (unsigned short*)(ws + OFF_XH);
    int pr = blk & 63, cib = (blk >> 6) & 3, bb = blk >> 8;
    int sp0 = pr * 64;
    const float* src = x + (unsigned)(bb * 256 + cib * 64) * 4096 + sp0;
#pragma unroll
    for (int rr = 0; rr < 16; ++rr) {
      int idx = rr * 256 + t;
      int ci = idx >> 6, px = idx & 63;
      lsm[ci][px] = src[ci * 4096 + px];
    }
    __syncthreads();
#pragma unroll
    for (int rr = 0; rr < 16; ++rr) {
      int idx = rr * 256 + t;
      int px = idx >> 6, ci = idx & 63;
      unsigned u = __float_as_uint(lsm[ci][px]);
      xh[(unsigned)(bb * 4096 + sp0 + px) * 256 + cib * 64 + ci] =
          (unsigned short)((u + 0x7FFF + ((u >> 16) & 1)) >> 16);
    }
  } else if (blk < 2251) {
    // KAN folding: contribution = fma(P',h,D') * exp2(h*fma(A,h,B));
    // A=Q, B=-2QT, P'=P0*2^C, D'=-P0*T*2^C, C=QT^2, Q=-0.5*log2e/s^2, P0=-kw/s.
    // Param layout coalesced: [ic][part8][o128][4f].
    int tid = (blk - 1024) * 256 + t;
    unsigned short* Wb = (unsigned short*)(ws + OFF_WB);
    if (tid < 294912) {
      int j = tid & 7, co = (tid >> 3) & 63, g = (tid >> 9) & 3, r = tid >> 11;
      int t9 = r % 9, q = r / 9, ck = q & 7, chh = q >> 3;
      int ci = ck * 32 + g * 8 + j, cog = chh * 64 + co;
      unsigned u = __float_as_uint(w1[(unsigned)(cog * 256 + ci) * 9 + t9]);
      Wb[tid] = (unsigned short)((u + 0x7FFF + ((u >> 16) & 1)) >> 16);
    } else if (tid < 294912 + 16384) {
      int i2 = tid - 294912;
      int i = i2 >> 7, o = i2 & 127;
      int ic = i >> 3, k = i & 7;
      float rs = 1.f / ks[o * 128 + i];
      float T  = kt[o * 128 + i];
      float A  = -0.7213475204444817f * rs * rs;   // Q
      float Bq = -2.f * A * T;
      float C  = A * T * T;
      float P0 = -rs * kw[o * 128 + i];
      float sc = exp2f(C);
      int khi = k >> 2, klo = k & 3;
      unsigned base = ((unsigned)ic * 8 * 128 + o) * 4 + klo;  // + part*512
      ws[OFF_PQT + base + (0 + khi) * 512] = A;
      ws[OFF_PQT + base + (2 + khi) * 512] = Bq;
      ws[OFF_PQT + base + (4 + khi) * 512] = P0 * sc;
      ws[OFF_PQT + base + (6 + khi) * 512] = -P0 * T * sc;
    } else if (tid < 294912 + 16384 + 2688) {
      int i3 = tid - 294912 - 16384;
      int nc = i3 >> 7, k = i3 & 127;
      ws[OFF_W2 + nc * 256 + k] = w2[nc * 128 + k];
    }
  } else {
    int nc = blk - 2251;
    if (t < 128) {
      float acc = 0.f;
      for (int o = 0; o < 128; ++o)
        acc = fmaf(w2[nc * 128 + o], kb[o * 128 + t], acc);
      ws[OFF_W2 + nc * 256 + 128 + t] = acc;
    }
  }
}

// ---------------- conv1 3x3 as bf16 MFMA implicit GEMM ---------------------
// grid 512 = bb(4) x y(64) x cohalf(2); block 256 = 4 waves; 2 blocks/CU.
// block tile 64M(1y x 64x) x 64N; wave tile 32Mx32N (Mr=2, Nr=2).
__global__ __launch_bounds__(256, 2) void conv1_mfma_k(
    const unsigned short* __restrict__ xh, const unsigned short* __restrict__ Wb,
    const float* __restrict__ b1, float* __restrict__ h) {
  __shared__ unsigned short Asm[3 * 66 * 40];  // [yrow3][x66][ci 32 pad40] 15.8KB
  __shared__ unsigned short Bsm[18432];        // [tap9][g4][co64][j8]      36.9KB
  int blk = blockIdx.x;
  int ch = blk & 1, y = (blk >> 1) & 63, bb = blk >> 7;
  int t = threadIdx.x;
  int wave = t >> 6, lane = t & 63;
  int wx = wave & 1, wn = wave >> 1;
  int l15 = lane & 15, lg = lane >> 4;

  if (t < 6) {  // zero x-halo columns (stay zero across chunks)
    int r = t >> 1, xl = (t & 1) * 65;
    float4 z = {0, 0, 0, 0};
    float4* p = (float4*)&Asm[(r * 66 + xl) * 40];
    p[0] = z; p[1] = z; p[2] = z; p[3] = z; p[4] = z;
  }

  f32x4 acc[2][2];
  f32x4 zz = {0.f, 0.f, 0.f, 0.f};
  acc[0][0] = zz; acc[0][1] = zz; acc[1][0] = zz; acc[1][1] = zz;

  int r_st = t >> 6, x_st = t & 63;
  int gy = y - 1 + r_st;
  bool arow = (r_st < 3);
  bool yok = arow & (gy >= 0) & (gy < 64);
  const unsigned short* asrc = xh + (unsigned)(bb * 4096 + gy * 64 + x_st) * 256;
  unsigned short* adst = &Asm[(r_st * 66 + x_st + 1) * 40];
  const unsigned short* bslab = Wb + ch * 8 * 18432;

  for (int ck = 0; ck < 8; ++ck) {
    float4 v0 = {0, 0, 0, 0}, v1 = v0, v2 = v0, v3 = v0;
    if (yok) {
      const float4* s = (const float4*)(asrc + ck * 32);
      v0 = s[0]; v1 = s[1]; v2 = s[2]; v3 = s[3];
    }
    if (arow) { float4* d = (float4*)adst; d[0] = v0; d[1] = v1; d[2] = v2; d[3] = v3; }
    {
      const float4* s = (const float4*)(bslab + ck * 18432);
      float4* d = (float4*)Bsm;
#pragma unroll
      for (int j = 0; j < 9; ++j) d[j * 256 + t] = s[j * 256 + t];
    }
    __syncthreads();
#pragma unroll
    for (int t9 = 0; t9 < 9; ++t9) {
      int ky = t9 / 3, kx = t9 % 3;
      s16x8 a[2], b[2];
      int abase = (ky * 66 + wx * 32 + l15 + kx) * 40 + lg * 8;
#pragma unroll
      for (int f = 0; f < 2; ++f)
        a[f] = *(const s16x8*)&Asm[abase + f * 640];
#pragma unroll
      for (int n = 0; n < 2; ++n)
        b[n] = *(const s16x8*)&Bsm[((t9 * 4 + lg) * 64 + wn * 32 + n * 16 + l15) * 8];
#pragma unroll
      for (int f = 0; f < 2; ++f)
#pragma unroll
        for (int n = 0; n < 2; ++n)
          acc[f][n] = __builtin_amdgcn_mfma_f32_16x16x32_bf16(a[f], b[n], acc[f][n], 0, 0, 0);
    }
    __syncthreads();
  }
  // epilogue: bias + relu, store h NHWC f32
#pragma unroll
  for (int n = 0; n < 2; ++n) {
    int co = ch * 64 + wn * 32 + n * 16 + l15;
    float bz = b1[co];
#pragma unroll
    for (int f = 0; f < 2; ++f) {
      int xbase = wx * 32 + f * 16 + lg * 4;
      float* dst = h + (unsigned)(bb * 4096 + y * 64 + xbase) * 128 + co;
#pragma unroll
      for (int r = 0; r < 4; ++r) {
        float v = acc[f][n][r] + bz;
        dst[r * 128] = v > 0.f ? v : 0.f;
      }
    }
  }
}

// ---------------- Wav-KAN + fused conv2, 2x wave oversubscription ----------
// r17: every r8-r16 wavkan launched exactly 8192 waves = 1.0x machine wave
// capacity — zero oversubscription explains the stuck 41-47% occupancy.
// 4-way i-split -> 16384 waves (2x). Block = 512 thr = 8 waves = ich(4) x
// oh(2), 8 n/block, grid 2048; wave = 64o x 8n x 32i. Param traffic per
// element unchanged. LDS 20.7KB -> 4 blocks/CU = 32 waves/CU = HW cap.
// Inner math body byte-identical to r12/r16 (proven best). conv2 tail kept.
__global__ __launch_bounds__(512) void wavkan_conv2_k(
    const float* __restrict__ h, const float* __restrict__ PQT,
    const float* __restrict__ w2c, const float* __restrict__ b2,
    float* __restrict__ out) {
  __shared__ float hsm[8][132];        // 4.2 KB
  __shared__ float red[3][2][8][64];   // 12 KB partial sums [ich-1][oh][n][lane]
  __shared__ float ksm[8][132];        // 4.2 KB k_wav rows
  int n0 = blockIdx.x * 8;
  int t = threadIdx.x;
  if (t < 256) {
    int row = t >> 5, c4 = (t & 31) * 4;
    *(float4*)&hsm[row][c4] = *(const float4*)&h[(unsigned)(n0 + row) * 128 + c4];
  }
  __syncthreads();

  int wave = t >> 6, lane = t & 63;
  int ich = wave & 3;            // i quarter: ic 4*ich .. 4*ich+3
  int oh  = wave >> 2;           // o half
  int o   = oh * 64 + lane;

  f32x2 accv[8];
#pragma unroll
  for (int n = 0; n < 8; ++n) accv[n] = (f32x2){0.f, 0.f};

  const float4* pq = (const float4*)PQT + o;   // + (ic*8+part)*128

  for (int ic = ich * 4; ic < ich * 4 + 4; ++ic) {
    const float4* pp = pq + (unsigned)ic * 1024;
    float4 r0 = pp[0],   r1 = pp[128], r2 = pp[256], r3 = pp[384],
           r4 = pp[512], r5 = pp[640], r6 = pp[768], r7 = pp[896];
    f32x2 A2[4] = {{r0.x, r0.y}, {r0.z, r0.w}, {r1.x, r1.y}, {r1.z, r1.w}};
    f32x2 B2[4] = {{r2.x, r2.y}, {r2.z, r2.w}, {r3.x, r3.y}, {r3.z, r3.w}};
    f32x2 P2[4] = {{r4.x, r4.y}, {r4.z, r4.w}, {r5.x, r5.y}, {r5.z, r5.w}};
    f32x2 D2[4] = {{r6.x, r6.y}, {r6.z, r6.w}, {r7.x, r7.y}, {r7.z, r7.w}};
    int i0 = ic * 8;
#pragma unroll
    for (int n = 0; n < 8; ++n) {
      float4 h0 = *(const float4*)&hsm[n][i0];           // broadcast ds_read
      float4 h1 = *(const float4*)&hsm[n][i0 + 4];
      f32x2 hh[4] = {{h0.x, h0.y}, {h0.z, h0.w}, {h1.x, h1.y}, {h1.z, h1.w}};
      f32x2 a2 = accv[n];
#pragma unroll
      for (int q = 0; q < 4; ++q) {
        f32x2 h2 = hh[q];
        f32x2 t2 = A2[q] * h2 + B2[q];     // v_pk_fma_f32
        f32x2 u2 = t2 * h2;                // v_pk_mul_f32
        f32x2 e2;
        e2.x = __builtin_amdgcn_exp2f(u2.x);
        e2.y = __builtin_amdgcn_exp2f(u2.y);
        f32x2 v2 = P2[q] * h2 + D2[q];     // v_pk_fma_f32
        a2 = v2 * e2 + a2;                 // v_pk_fma_f32
      }
      accv[n] = a2;
    }
  }

  // reduce i-quarters: ich 1..3 publish; barrier; ich 0 combines -> ksm.
  if (ich) {
#pragma unroll
    for (int n = 0; n < 8; ++n)
      red[ich - 1][oh][n][lane] = accv[n].x + accv[n].y;
  }
  __syncthreads();
  if (!ich) {
#pragma unroll
    for (int n = 0; n < 8; ++n) {
      ksm[n][o] = (accv[n].x + accv[n].y) + red[0][oh][n][lane] +
                  red[1][oh][n][lane] + red[2][oh][n][lane];
    }
  }
  // silu(h) in place (all hsm reads completed before the barrier above)
  if (t < 256) {
    int n = t >> 5, c4 = (t & 31) * 4;
    float4 v = *(float4*)&hsm[n][c4];
    float4 s;
    s.x = v.x * __builtin_amdgcn_rcpf(1.f + __builtin_amdgcn_exp2f(-LOG2E * v.x));
    s.y = v.y * __builtin_amdgcn_rcpf(1.f + __builtin_amdgcn_exp2f(-LOG2E * v.y));
    s.z = v.z * __builtin_amdgcn_rcpf(1.f + __builtin_amdgcn_exp2f(-LOG2E * v.z));
    s.w = v.w * __builtin_amdgcn_rcpf(1.f + __builtin_amdgcn_exp2f(-LOG2E * v.w));
    *(float4*)&hsm[n][c4] = s;
  }
  __syncthreads();

  // conv2 tail: 168 threads, thread (g,n): out[bb][g][sp] over K=[ksm|silu h]
  if (t < 168) {
    int n = t & 7, g = t >> 3;
    const float* w0 = w2c + g * 256;
    const float* kr = &ksm[n][0];
    const float* hr = &hsm[n][0];
    float a0 = 0.f;
#pragma unroll 4
    for (int k4 = 0; k4 < 32; ++k4) {
      float4 kv = *(const float4*)&kr[k4 * 4];
      float4 w = *(const float4*)&w0[k4 * 4];
      a0 += kv.x * w.x + kv.y * w.y + kv.z * w.z + kv.w * w.w;
    }
#pragma unroll 4
    for (int k4 = 0; k4 < 32; ++k4) {
      float4 hv = *(const float4*)&hr[k4 * 4];
      float4 w = *(const float4*)&w0[128 + k4 * 4];
      a0 += hv.x * w.x + hv.y * w.y + hv.z * w.z + hv.w * w.w;
    }
    int gn = n0 + n, bb = gn >> 12, sp = gn & 4095;
    out[(unsigned)(bb * 21 + g) * 4096 + sp] = a0 + b2[g];
  }
}

// ---------------- launch ---------------------------------------------------
extern "C" void kernel_launch(void* const* d_in, const int* in_sizes, int n_in,
                              void* d_out, int out_size, void* d_ws, size_t ws_size,
                              hipStream_t stream) {
  const float* x  = (const float*)d_in[0];
  const float* w1 = (const float*)d_in[1];
  const float* b1 = (const float*)d_in[2];
  const float* ks = (const float*)d_in[3];
  const float* kt = (const float*)d_in[4];
  const float* kw = (const float*)d_in[5];
  const float* kb = (const float*)d_in[6];
  const float* w2 = (const float*)d_in[7];
  const float* b2 = (const float*)d_in[8];
  float* out = (float*)d_out;
  float* ws  = (float*)d_ws;

  prep_all_k<<<2272, 256, 0, stream>>>(x, w1, ks, kt, kw, kb, w2, ws);
  conv1_mfma_k<<<512, 256, 0, stream>>>((const unsigned short*)(ws + OFF_XH),
                                        (const unsigned short*)(ws + OFF_WB),
                                        b1, ws + OFF_H);
  wavkan_conv2_k<<<2048, 512, 0, stream>>>(ws + OFF_H, ws + OFF_PQT,
                                           ws + OFF_W2, b2, out);
}

// Round 18
// 82.603 us; speedup vs baseline: 1.1837x; 1.0242x over previous
//
#include <hip/hip_runtime.h>
#include <math.h>

typedef __attribute__((ext_vector_type(8))) short s16x8;
typedef __attribute__((ext_vector_type(4))) float f32x4;
typedef __attribute__((ext_vector_type(2))) float f32x2;

#define LOG2E 1.4426950408889634f

// ---- workspace layout (float offsets) ----
#define OFF_XH   0           // xh bf16 NHWC [4][4096][256] = 2,097,152 floats
#define OFF_WB   2097152     // conv1 weights bf16 MFMA layout [ch2][ck8][tap9][g4][co64][j8]
#define OFF_PQT  2244608     // [ic16][part8][o128][4] = coalesced {A,B,P',D'}
#define OFF_W2   2310144     // W2cat [21][256] = [w2 | w2@base_w]
#define OFF_H    2315520     // h f32 NHWC [16384][128]

// ---------------- fused prologue: transpose x | prep weights | w2b ---------
__global__ __launch_bounds__(256) void prep_all_k(
    const float* __restrict__ x, const float* __restrict__ w1,
    const float* __restrict__ ks, const float* __restrict__ kt,
    const float* __restrict__ kw, const float* __restrict__ kb,
    const float* __restrict__ w2, float* __restrict__ ws) {
  int blk = blockIdx.x;
  int t = threadIdx.x;
  if (blk < 1024) {
    __shared__ float lsm[64][65];
    unsigned short* xh = (unsigned short*)(ws + OFF_XH);
    int pr = blk & 63, cib = (blk >> 6) & 3, bb = blk >> 8;
    int sp0 = pr * 64;
    const float* src = x + (unsigned)(bb * 256 + cib * 64) * 4096 + sp0;
#pragma unroll
    for (int rr = 0; rr < 16; ++rr) {
      int idx = rr * 256 + t;
      int ci = idx >> 6, px = idx & 63;
      lsm[ci][px] = src[ci * 4096 + px];
    }
    __syncthreads();
#pragma unroll
    for (int rr = 0; rr < 16; ++rr) {
      int idx = rr * 256 + t;
      int px = idx >> 6, ci = idx & 63;
      unsigned u = __float_as_uint(lsm[ci][px]);
      xh[(unsigned)(bb * 4096 + sp0 + px) * 256 + cib * 64 + ci] =
          (unsigned short)((u + 0x7FFF + ((u >> 16) & 1)) >> 16);
    }
  } else if (blk < 2251) {
    // KAN folding: contribution = fma(P',h,D') * exp2(h*fma(A,h,B));
    // A=Q, B=-2QT, P'=P0*2^C, D'=-P0*T*2^C, C=QT^2, Q=-0.5*log2e/s^2, P0=-kw/s.
    // Param layout coalesced: [ic][part8][o128][4f].
    int tid = (blk - 1024) * 256 + t;
    unsigned short* Wb = (unsigned short*)(ws + OFF_WB);
    if (tid < 294912) {
      int j = tid & 7, co = (tid >> 3) & 63, g = (tid >> 9) & 3, r = tid >> 11;
      int t9 = r % 9, q = r / 9, ck = q & 7, chh = q >> 3;
      int ci = ck * 32 + g * 8 + j, cog = chh * 64 + co;
      unsigned u = __float_as_uint(w1[(unsigned)(cog * 256 + ci) * 9 + t9]);
      Wb[tid] = (unsigned short)((u + 0x7FFF + ((u >> 16) & 1)) >> 16);
    } else if (tid < 294912 + 16384) {
      int i2 = tid - 294912;
      int i = i2 >> 7, o = i2 & 127;
      int ic = i >> 3, k = i & 7;
      float rs = 1.f / ks[o * 128 + i];
      float T  = kt[o * 128 + i];
      float A  = -0.7213475204444817f * rs * rs;   // Q
      float Bq = -2.f * A * T;
      float C  = A * T * T;
      float P0 = -rs * kw[o * 128 + i];
      float sc = exp2f(C);
      int khi = k >> 2, klo = k & 3;
      unsigned base = ((unsigned)ic * 8 * 128 + o) * 4 + klo;  // + part*512
      ws[OFF_PQT + base + (0 + khi) * 512] = A;
      ws[OFF_PQT + base + (2 + khi) * 512] = Bq;
      ws[OFF_PQT + base + (4 + khi) * 512] = P0 * sc;
      ws[OFF_PQT + base + (6 + khi) * 512] = -P0 * T * sc;
    } else if (tid < 294912 + 16384 + 2688) {
      int i3 = tid - 294912 - 16384;
      int nc = i3 >> 7, k = i3 & 127;
      ws[OFF_W2 + nc * 256 + k] = w2[nc * 128 + k];
    }
  } else {
    int nc = blk - 2251;
    if (t < 128) {
      float acc = 0.f;
      for (int o = 0; o < 128; ++o)
        acc = fmaf(w2[nc * 128 + o], kb[o * 128 + t], acc);
      ws[OFF_W2 + nc * 256 + 128 + t] = acc;
    }
  }
}

// ---------------- conv1 3x3 as bf16 MFMA implicit GEMM ---------------------
// r18: bigger wave tile to cut the LDS-read floor. Old shape read 1KB LDS
// per MFMA (4 reads / 4 MFMA per tap) -> ~590MB total -> 11.3us LDS floor
// + staging exposure = ~23us measured. New: block 128M(2y x 64x) x 64N,
// 4 waves, wave tile 64M x 32N (Mr=4, Nr=2): 6 reads / 8 MFMA = 0.75KB/MFMA
// -> 8.5us floor, 2x MFMA per barrier. grid 256 = bb(4) x yt(32) x ch(2).
// LDS 58KB. Halo columns (gx=-1,64) are always OOB-zero: zeroed once.
__global__ __launch_bounds__(256, 2) void conv1_mfma_k(
    const unsigned short* __restrict__ xh, const unsigned short* __restrict__ Wb,
    const float* __restrict__ b1, float* __restrict__ h) {
  __shared__ unsigned short Asm[4 * 66 * 40];  // [yrow4][x66][ci 32 pad40] 21.1KB
  __shared__ unsigned short Bsm[18432];        // [tap9][g4][co64][j8]      36.9KB
  int blk = blockIdx.x;
  int ch = blk & 1, yt = (blk >> 1) & 31, bb = blk >> 6;
  int y0 = yt * 2;
  int t = threadIdx.x;
  int wave = t >> 6, lane = t & 63;
  int wn = wave & 1, wm = wave >> 1;   // wm = output y-row within tile
  int l15 = lane & 15, lg = lane >> 4;

  if (t < 8) {  // zero x-halo columns (always OOB; stay zero across chunks)
    int r = t >> 1, xl = (t & 1) * 65;
    float4 z = {0, 0, 0, 0};
    float4* p = (float4*)&Asm[(r * 66 + xl) * 40];
    p[0] = z; p[1] = z; p[2] = z; p[3] = z; p[4] = z;
  }

  f32x4 acc[4][2];
  f32x4 zz = {0.f, 0.f, 0.f, 0.f};
#pragma unroll
  for (int f = 0; f < 4; ++f) { acc[f][0] = zz; acc[f][1] = zz; }

  int r_st = t >> 6, x_st = t & 63;    // 4 rows x 64 px staging map
  int gy = y0 - 1 + r_st;
  bool yok = (gy >= 0) & (gy < 64);
  const unsigned short* asrc = xh + (unsigned)(bb * 4096 + gy * 64 + x_st) * 256;
  unsigned short* adst = &Asm[(r_st * 66 + x_st + 1) * 40];
  const unsigned short* bslab = Wb + ch * 8 * 18432;

  for (int ck = 0; ck < 8; ++ck) {
    float4 v0 = {0, 0, 0, 0}, v1 = v0, v2 = v0, v3 = v0;
    if (yok) {
      const float4* s = (const float4*)(asrc + ck * 32);
      v0 = s[0]; v1 = s[1]; v2 = s[2]; v3 = s[3];
    }
    { float4* d = (float4*)adst; d[0] = v0; d[1] = v1; d[2] = v2; d[3] = v3; }
    {
      const float4* s = (const float4*)(bslab + ck * 18432);
      float4* d = (float4*)Bsm;
#pragma unroll
      for (int j = 0; j < 9; ++j) d[j * 256 + t] = s[j * 256 + t];
    }
    __syncthreads();
#pragma unroll
    for (int t9 = 0; t9 < 9; ++t9) {
      int ky = t9 / 3, kx = t9 % 3;
      s16x8 a[4], b[2];
      int abase = ((wm + ky) * 66 + l15 + kx) * 40 + lg * 8;
#pragma unroll
      for (int f = 0; f < 4; ++f)
        a[f] = *(const s16x8*)&Asm[abase + f * 640];
#pragma unroll
      for (int n = 0; n < 2; ++n)
        b[n] = *(const s16x8*)&Bsm[((t9 * 4 + lg) * 64 + wn * 32 + n * 16 + l15) * 8];
#pragma unroll
      for (int f = 0; f < 4; ++f)
#pragma unroll
        for (int n = 0; n < 2; ++n)
          acc[f][n] = __builtin_amdgcn_mfma_f32_16x16x32_bf16(a[f], b[n], acc[f][n], 0, 0, 0);
    }
    __syncthreads();
  }
  // epilogue: bias + relu, store h NHWC f32
#pragma unroll
  for (int n = 0; n < 2; ++n) {
    int co = ch * 64 + wn * 32 + n * 16 + l15;
    float bz = b1[co];
#pragma unroll
    for (int f = 0; f < 4; ++f) {
      int xbase = f * 16 + lg * 4;
      float* dst = h + (unsigned)(bb * 4096 + (y0 + wm) * 64 + xbase) * 128 + co;
#pragma unroll
      for (int r = 0; r < 4; ++r) {
        float v = acc[f][n][r] + bz;
        dst[r * 128] = v > 0.f ? v : 0.f;
      }
    }
  }
}

// ---------------- Wav-KAN + fused conv2 (r17 structure, proven) ------------
__global__ __launch_bounds__(512) void wavkan_conv2_k(
    const float* __restrict__ h, const float* __restrict__ PQT,
    const float* __restrict__ w2c, const float* __restrict__ b2,
    float* __restrict__ out) {
  __shared__ float hsm[8][132];        // 4.2 KB
  __shared__ float red[3][2][8][64];   // 12 KB partial sums [ich-1][oh][n][lane]
  __shared__ float ksm[8][132];        // 4.2 KB k_wav rows
  int n0 = blockIdx.x * 8;
  int t = threadIdx.x;
  if (t < 256) {
    int row = t >> 5, c4 = (t & 31) * 4;
    *(float4*)&hsm[row][c4] = *(const float4*)&h[(unsigned)(n0 + row) * 128 + c4];
  }
  __syncthreads();

  int wave = t >> 6, lane = t & 63;
  int ich = wave & 3;            // i quarter: ic 4*ich .. 4*ich+3
  int oh  = wave >> 2;           // o half
  int o   = oh * 64 + lane;

  f32x2 accv[8];
#pragma unroll
  for (int n = 0; n < 8; ++n) accv[n] = (f32x2){0.f, 0.f};

  const float4* pq = (const float4*)PQT + o;   // + (ic*8+part)*128

  for (int ic = ich * 4; ic < ich * 4 + 4; ++ic) {
    const float4* pp = pq + (unsigned)ic * 1024;
    float4 r0 = pp[0],   r1 = pp[128], r2 = pp[256], r3 = pp[384],
           r4 = pp[512], r5 = pp[640], r6 = pp[768], r7 = pp[896];
    f32x2 A2[4] = {{r0.x, r0.y}, {r0.z, r0.w}, {r1.x, r1.y}, {r1.z, r1.w}};
    f32x2 B2[4] = {{r2.x, r2.y}, {r2.z, r2.w}, {r3.x, r3.y}, {r3.z, r3.w}};
    f32x2 P2[4] = {{r4.x, r4.y}, {r4.z, r4.w}, {r5.x, r5.y}, {r5.z, r5.w}};
    f32x2 D2[4] = {{r6.x, r6.y}, {r6.z, r6.w}, {r7.x, r7.y}, {r7.z, r7.w}};
    int i0 = ic * 8;
#pragma unroll
    for (int n = 0; n < 8; ++n) {
      float4 h0 = *(const float4*)&hsm[n][i0];           // broadcast ds_read
      float4 h1 = *(const float4*)&hsm[n][i0 + 4];
      f32x2 hh[4] = {{h0.x, h0.y}, {h0.z, h0.w}, {h1.x, h1.y}, {h1.z, h1.w}};
      f32x2 a2 = accv[n];
#pragma unroll
      for (int q = 0; q < 4; ++q) {
        f32x2 h2 = hh[q];
        f32x2 t2 = A2[q] * h2 + B2[q];     // v_pk_fma_f32
        f32x2 u2 = t2 * h2;                // v_pk_mul_f32
        f32x2 e2;
        e2.x = __builtin_amdgcn_exp2f(u2.x);
        e2.y = __builtin_amdgcn_exp2f(u2.y);
        f32x2 v2 = P2[q] * h2 + D2[q];     // v_pk_fma_f32
        a2 = v2 * e2 + a2;                 // v_pk_fma_f32
      }
      accv[n] = a2;
    }
  }

  // reduce i-quarters: ich 1..3 publish; barrier; ich 0 combines -> ksm.
  if (ich) {
#pragma unroll
    for (int n = 0; n < 8; ++n)
      red[ich - 1][oh][n][lane] = accv[n].x + accv[n].y;
  }
  __syncthreads();
  if (!ich) {
#pragma unroll
    for (int n = 0; n < 8; ++n) {
      ksm[n][o] = (accv[n].x + accv[n].y) + red[0][oh][n][lane] +
                  red[1][oh][n][lane] + red[2][oh][n][lane];
    }
  }
  // silu(h) in place (all hsm reads completed before the barrier above)
  if (t < 256) {
    int n = t >> 5, c4 = (t & 31) * 4;
    float4 v = *(float4*)&hsm[n][c4];
    float4 s;
    s.x = v.x * __builtin_amdgcn_rcpf(1.f + __builtin_amdgcn_exp2f(-LOG2E * v.x));
    s.y = v.y * __builtin_amdgcn_rcpf(1.f + __builtin_amdgcn_exp2f(-LOG2E * v.y));
    s.z = v.z * __builtin_amdgcn_rcpf(1.f + __builtin_amdgcn_exp2f(-LOG2E * v.z));
    s.w = v.w * __builtin_amdgcn_rcpf(1.f + __builtin_amdgcn_exp2f(-LOG2E * v.w));
    *(float4*)&hsm[n][c4] = s;
  }
  __syncthreads();

  // conv2 tail: 168 threads, thread (g,n): out[bb][g][sp] over K=[ksm|silu h]
  if (t < 168) {
    int n = t & 7, g = t >> 3;
    const float* w0 = w2c + g * 256;
    const float* kr = &ksm[n][0];
    const float* hr = &hsm[n][0];
    float a0 = 0.f;
#pragma unroll 4
    for (int k4 = 0; k4 < 32; ++k4) {
      float4 kv = *(const float4*)&kr[k4 * 4];
      float4 w = *(const float4*)&w0[k4 * 4];
      a0 += kv.x * w.x + kv.y * w.y + kv.z * w.z + kv.w * w.w;
    }
#pragma unroll 4
    for (int k4 = 0; k4 < 32; ++k4) {
      float4 hv = *(const float4*)&hr[k4 * 4];
      float4 w = *(const float4*)&w0[128 + k4 * 4];
      a0 += hv.x * w.x + hv.y * w.y + hv.z * w.z + hv.w * w.w;
    }
    int gn = n0 + n, bb = gn >> 12, sp = gn & 4095;
    out[(unsigned)(bb * 21 + g) * 4096 + sp] = a0 + b2[g];
  }
}

// ---------------- launch ---------------------------------------------------
extern "C" void kernel_launch(void* const* d_in, const int* in_sizes, int n_in,
                              void* d_out, int out_size, void* d_ws, size_t ws_size,
                              hipStream_t stream) {
  const float* x  = (const float*)d_in[0];
  const float* w1 = (const float*)d_in[1];
  const float* b1 = (const float*)d_in[2];
  const float* ks = (const float*)d_in[3];
  const float* kt = (const float*)d_in[4];
  const float* kw = (const float*)d_in[5];
  const float* kb = (const float*)d_in[6];
  const float* w2 = (const float*)d_in[7];
  const float* b2 = (const float*)d_in[8];
  float* out = (float*)d_out;
  float* ws  = (float*)d_ws;

  prep_all_k<<<2272, 256, 0, stream>>>(x, w1, ks, kt, kw, kb, w2, ws);
  conv1_mfma_k<<<256, 256, 0, stream>>>((const unsigned short*)(ws + OFF_XH),
                                        (const unsigned short*)(ws + OFF_WB),
                                        b1, ws + OFF_H);
  wavkan_conv2_k<<<2048, 512, 0, stream>>>(ws + OFF_H, ws + OFF_PQT,
                                           ws + OFF_W2, b2, out);
}